// Round 11
// baseline (321.097 us; speedup 1.0000x reference)
//
#include <hip/hip_runtime.h>
#include <hip/hip_bf16.h>
#include <math.h>

typedef __bf16 bf16;
typedef bf16 bf16x8 __attribute__((ext_vector_type(8)));
typedef bf16 bf16x4v __attribute__((ext_vector_type(4)));
typedef float f32x4 __attribute__((ext_vector_type(4)));

#define GLD16(g, l) __builtin_amdgcn_global_load_lds(                          \
    (__attribute__((address_space(1))) void*)(g),                              \
    (__attribute__((address_space(3))) void*)(l), 16, 0, 0)

#define MFMA16(a, b, c) __builtin_amdgcn_mfma_f32_16x16x32_bf16((a), (b), (c), 0, 0, 0)

#if __has_builtin(__builtin_amdgcn_exp2f)
#define EXP2F(x) __builtin_amdgcn_exp2f(x)
#else
#define EXP2F(x) exp2f(x)
#endif

__device__ __forceinline__ f32x4 shfl_xor4(f32x4 a, int m) {
  f32x4 r;
  #pragma unroll
  for (int i = 0; i < 4; i++) r[i] = __shfl_xor(a[i], m);
  return r;
}

// ---------------- fused prep: cast x->bf16 + 4 weight transposes in ONE launch ----------------
// (verified R6/R8: absmax unchanged)
__global__ __launch_bounds__(256) void prep(const float* __restrict__ x,
                                            const float* __restrict__ Wq,
                                            const float* __restrict__ Wk,
                                            const float* __restrict__ Wv,
                                            const float* __restrict__ Wo,
                                            bf16* __restrict__ Xb,
                                            bf16* __restrict__ Wqkvt,
                                            bf16* __restrict__ Wot,
                                            float qscale) {
  const int id = blockIdx.x;
  const int tid = threadIdx.x;
  if (id >= 10240) {  // vector cast
    int i = (id - 10240) * 256 + tid;
    float4 v = ((const float4*)x)[i];
    bf16x4v o;
    o.x = (bf16)v.x; o.y = (bf16)v.y; o.z = (bf16)v.z; o.w = (bf16)v.w;
    ((bf16x4v*)Xb)[i] = o;
    return;
  }
  __shared__ float t[32][33];
  const float* in; bf16* out; int colsIn, outRowOff, bx, by; float scale;
  if (id < 4096)      { in = Wq; out = Wqkvt; colsIn = 2048; outRowOff = 0;    scale = qscale; bx = id & 63;          by = id >> 6; }
  else if (id < 5120) { in = Wk; out = Wqkvt; colsIn = 512;  outRowOff = 2048; scale = 1.0f;   bx = (id - 4096) & 15; by = (id - 4096) >> 4; }
  else if (id < 6144) { in = Wv; out = Wqkvt; colsIn = 512;  outRowOff = 2560; scale = 1.0f;   bx = (id - 5120) & 15; by = (id - 5120) >> 4; }
  else                { in = Wo; out = Wot;   colsIn = 2048; outRowOff = 0;    scale = 1.0f;   bx = (id - 6144) & 63; by = (id - 6144) >> 6; }
  const int c0 = bx * 32, r0 = by * 32;
  const int tx = tid & 31, ty = tid >> 5;
  #pragma unroll
  for (int i = 0; i < 32; i += 8)
    t[ty + i][tx] = in[(size_t)(r0 + ty + i) * colsIn + (c0 + tx)];
  __syncthreads();
  #pragma unroll
  for (int i = 0; i < 32; i += 8)
    out[(size_t)(outRowOff + c0 + ty + i) * 2048 + (r0 + tx)] = (bf16)(t[tx][ty + i] * scale);
}

// ---------------- m97-style GEMM (gemm1): A[M][K] bf16, Bt[N][K] bf16 -> C[M][N] ----------------
// One-tile-per-block, 768 blocks = 3 blocks/CU co-resident (verified R8).
// V col-tiles (colBase>=2560) write transposed bf16 directly to Vg[d][n] and skip the
// never-read QKV V-region (replaces transpose_v kernel; verified R6/R8).
__global__ __launch_bounds__(256, 2) void gemm_bt(const bf16* __restrict__ A,
                                                  const bf16* __restrict__ Bt,
                                                  bf16* __restrict__ C,
                                                  bf16* __restrict__ Vg,
                                                  int N, int K) {
  __shared__ __attribute__((aligned(16))) bf16 As[128 * 32];
  __shared__ __attribute__((aligned(16))) bf16 Bs[128 * 32];
  const int tid = threadIdx.x;
  const int lane = tid & 63;
  const int wave = tid >> 6;
  const int wm = wave >> 1, wn = wave & 1;
  const int l15 = lane & 15, quad = lane >> 4;
  const int rowBase = blockIdx.y * 128;
  const int colBase = blockIdx.x * 128;

  f32x4 acc[4][4] = {};

  const int cb0 = wave * 64;
  const int c0 = cb0 + lane;
  const int c1 = c0 + 256;
  const bf16* a0 = A + (size_t)(rowBase + (c0 >> 2)) * K + (c0 & 3) * 8;
  const bf16* a1 = A + (size_t)(rowBase + (c1 >> 2)) * K + (c1 & 3) * 8;
  const bf16* b0 = Bt + (size_t)(colBase + (c0 >> 2)) * K + (c0 & 3) * 8;
  const bf16* b1 = Bt + (size_t)(colBase + (c1 >> 2)) * K + (c1 & 3) * 8;
  bf16* lA0 = &As[cb0 * 8];
  bf16* lA1 = &As[(cb0 + 256) * 8];
  bf16* lB0 = &Bs[cb0 * 8];
  bf16* lB1 = &Bs[(cb0 + 256) * 8];

  for (int k0 = 0; k0 < K; k0 += 32) {
    GLD16(a0 + k0, lA0);
    GLD16(a1 + k0, lA1);
    GLD16(b0 + k0, lB0);
    GLD16(b1 + k0, lB1);
    __syncthreads();
    bf16x8 af[4], bfr[4];
    #pragma unroll
    for (int i = 0; i < 4; i++)
      af[i] = *(const bf16x8*)&As[(wm * 64 + i * 16 + l15) * 32 + quad * 8];
    #pragma unroll
    for (int i = 0; i < 4; i++)
      bfr[i] = *(const bf16x8*)&Bs[(wn * 64 + i * 16 + l15) * 32 + quad * 8];
    #pragma unroll
    for (int i = 0; i < 4; i++)
      #pragma unroll
      for (int j = 0; j < 4; j++)
        acc[i][j] = MFMA16(af[i], bfr[j], acc[i][j]);
    __syncthreads();
  }

  if (colBase >= 2560) {
    // transposed V write: Vg[(b*4+kvh)*128 + d][n] = acc
    const int kvh = (colBase - 2560) >> 7;
    #pragma unroll
    for (int i = 0; i < 4; i++) {
      int row = rowBase + wm * 64 + i * 16 + quad * 4;
      int bb = row >> 11;
      int n0 = row & 2047;
      #pragma unroll
      for (int j = 0; j < 4; j++) {
        int d = wn * 64 + j * 16 + l15;
        bf16x4v o;
        #pragma unroll
        for (int r = 0; r < 4; r++) o[r] = (bf16)acc[i][j][r];
        *(bf16x4v*)&Vg[((size_t)(bb * 4 + kvh) * 128 + d) * 2048 + n0] = o;
      }
    }
  } else {
    #pragma unroll
    for (int i = 0; i < 4; i++) {
      int row = rowBase + wm * 64 + i * 16 + quad * 4;
      #pragma unroll
      for (int j = 0; j < 4; j++) {
        int col = colBase + wn * 64 + j * 16 + l15;
        #pragma unroll
        for (int r = 0; r < 4; r++)
          C[(size_t)(row + r) * N + col] = (bf16)acc[i][j][r];
      }
    }
  }
}

// ---------------- gemm2: 64x128-tile, 128-thread (2-wave) variant -> f32 out ----------------
// R10 analysis: gemm2's 512 x 128^2 tiles = exactly 2 blocks/CU -- the same 2/CU config
// that cost gemm1 +27us in R6 (cross-block wave overlap IS this structure's pipeline).
// 64x128 tiles -> 1024 blocks, ~4+/CU resident (LDS 12KB, ~60 VGPR). Per-wave work and
// K-step accumulation order are IDENTICAL to gemm_bt (wm=0, 2 waves) -> bit-identical C.
// Staging: 6 GLD16/thread (2 A-rounds + 4 B-rounds), slot = p*128 + tid, wave-uniform bases.
__global__ __launch_bounds__(128, 2) void gemm_bt64(const bf16* __restrict__ A,
                                                    const bf16* __restrict__ Bt,
                                                    float* __restrict__ C,
                                                    int N, int K) {
  __shared__ __attribute__((aligned(16))) bf16 As[64 * 32];
  __shared__ __attribute__((aligned(16))) bf16 Bs[128 * 32];
  const int tid = threadIdx.x;         // 0..127
  const int lane = tid & 63;
  const int wave = tid >> 6;           // 0..1
  const int l15 = lane & 15, quad = lane >> 4;
  const int rowBase = blockIdx.y * 64;
  const int colBase = blockIdx.x * 128;

  f32x4 acc[4][4] = {};

  // staging pointers: slot s = p*128 + tid; row = s>>2, k-chunk = s&3
  const bf16* aP[2]; bf16* lAp[2];
  #pragma unroll
  for (int p = 0; p < 2; p++) {
    int s = p * 128 + tid;
    aP[p] = A + (size_t)(rowBase + (s >> 2)) * K + (s & 3) * 8;
    lAp[p] = &As[(p * 128 + wave * 64) * 8];
  }
  const bf16* bP[4]; bf16* lBp[4];
  #pragma unroll
  for (int p = 0; p < 4; p++) {
    int s = p * 128 + tid;
    bP[p] = Bt + (size_t)(colBase + (s >> 2)) * K + (s & 3) * 8;
    lBp[p] = &Bs[(p * 128 + wave * 64) * 8];
  }

  for (int k0 = 0; k0 < K; k0 += 32) {
    #pragma unroll
    for (int p = 0; p < 2; p++) GLD16(aP[p] + k0, lAp[p]);
    #pragma unroll
    for (int p = 0; p < 4; p++) GLD16(bP[p] + k0, lBp[p]);
    __syncthreads();
    bf16x8 af[4], bfr[4];
    #pragma unroll
    for (int i = 0; i < 4; i++)
      af[i] = *(const bf16x8*)&As[(i * 16 + l15) * 32 + quad * 8];
    #pragma unroll
    for (int i = 0; i < 4; i++)
      bfr[i] = *(const bf16x8*)&Bs[(wave * 64 + i * 16 + l15) * 32 + quad * 8];
    #pragma unroll
    for (int i = 0; i < 4; i++)
      #pragma unroll
      for (int j = 0; j < 4; j++)
        acc[i][j] = MFMA16(af[i], bfr[j], acc[i][j]);
    __syncthreads();
  }

  #pragma unroll
  for (int i = 0; i < 4; i++) {
    int row = rowBase + i * 16 + quad * 4;
    #pragma unroll
    for (int j = 0; j < 4; j++) {
      int col = colBase + wave * 64 + j * 16 + l15;
      #pragma unroll
      for (int r = 0; r < 4; r++)
        C[(size_t)(row + r) * N + col] = acc[i][j][r];
    }
  }
}

// ---------------- flash-style GQA attention (R8-exact, verified 83.3us) ----------------
// setprio REVERTED (R10: +5us regression -- 4-wave barrier-lockstep blocks are the m190
// null/negative regime, not m191's independent-block regime).
#define MASKV (-1e30f)

// entry code = qt*4 + split*2 + half. CU c gets entries {c>>5, (c>>5)+8, (c>>5)+16}:
// every group of 3 sums to 34 tiles; longest block 20 tiles.
__device__ const unsigned char BMAP[22] = {
  28, 58, 24, 50, 20, 46, 36, 32,      // e0..e7:  qt7f qt14h0 qt6f qt12h0 qt5f qt11h0 qt9f qt8f
  62, 59, 54, 51, 47, 42, 55, 63,      // e8..e15: qt15h0 qt14h1 qt13h0 qt12h1 qt11h1 qt10h0 qt13h1 qt15h1
  0, 4, 8, 12, 16, 43                  // e16..e21: qt0f qt1f qt2f qt3f qt4f qt10h1
};

#define SLOT_F32 16640  // 128*128 Oacc + 128 m + 128 l

__global__ __launch_bounds__(256, 2) void gqa_attn(const bf16* __restrict__ QKV,
                                                   const bf16* __restrict__ Vg,
                                                   bf16* __restrict__ Obf,
                                                   float* __restrict__ Part) {
  __shared__ __attribute__((aligned(16))) bf16 Kl[64 * 128];   // [key][hd], chunk c' = c ^ (key&7)
  __shared__ __attribute__((aligned(16))) bf16 Vt[128 * 64];   // [hd][key], chunk c' = c ^ (d&7)
  __shared__ __attribute__((aligned(16))) bf16 Pl[4][32 * 68]; // per-wave P, stride 68

  const int tid = threadIdx.x;
  const int lane = tid & 63;
  const int wave = tid >> 6;
  const int l15 = lane & 15, quad = lane >> 4;

  const int e = BMAP[blockIdx.x >> 5];
  const int bh = blockIdx.x & 31;
  const int qt = e >> 2;
  const int split = (e >> 1) & 1;
  const int half = e & 1;
  const int b = bh >> 4, h = bh & 15, kvh = h >> 2;
  const int q0 = qt * 128;
  const int nkt = 2 * qt + 2;
  const int kt_lo = (split && half) ? (nkt >> 1) : 0;
  const int kt_hi = (split && !half) ? (nkt >> 1) : nkt;

  const size_t rs = 3072;
  const bf16* Qb  = QKV + (size_t)b * 2048 * rs + h * 128;
  const bf16* Kb  = QKV + (size_t)b * 2048 * rs + 2048 + kvh * 128;
  const bf16* Vgb = Vg + (size_t)(b * 4 + kvh) * 128 * 2048;

  // Q fragments (already scaled): wave owns rows [q0+wave*32, +32)
  bf16x8 qf[2][4];
  #pragma unroll
  for (int mt = 0; mt < 2; mt++) {
    int row = q0 + wave * 32 + mt * 16 + l15;
    #pragma unroll
    for (int ks = 0; ks < 4; ks++)
      qf[mt][ks] = *(const bf16x8*)&Qb[(size_t)row * rs + ks * 32 + quad * 8];
  }

  // constant all-ones B-fragment for the l-accumulator MFMA
  bf16x8 ones8;
  #pragma unroll
  for (int i = 0; i < 8; i++) ones8[i] = (bf16)1.0f;

  // DMA staging pointers: swizzle folded into per-lane GLOBAL address; LDS base wave-uniform.
  const bf16* kp[4]; const bf16* vp[4];
  bf16* kl[4]; bf16* vl[4];
  #pragma unroll
  for (int t = 0; t < 4; t++) {
    int keyl = wave * 16 + t * 4 + (lane >> 4);
    int ck = (lane & 15) ^ (4 * (t & 1) + (lane >> 4));  // (keyl&7) = 4*(t&1)+(lane>>4)
    kp[t] = Kb + (size_t)(kt_lo * 64 + keyl) * rs + ck * 8;
    kl[t] = &Kl[(wave * 16 + t * 4) * 128];
    int dl = wave * 32 + t * 8 + (lane >> 3);
    int cv = (lane & 7) ^ (lane >> 3);                   // (dl&7) = lane>>3
    vp[t] = Vgb + (size_t)dl * 2048 + kt_lo * 64 + cv * 8;
    vl[t] = &Vt[(wave * 32 + t * 8) * 64];
  }

  f32x4 oacc[2][8] = {};
  f32x4 lacc[2] = {};
  f32x4 mrow[2];
  #pragma unroll
  for (int mt = 0; mt < 2; mt++)
    #pragma unroll
    for (int r = 0; r < 4; r++) mrow[mt][r] = MASKV;

  const int myrow_hi = q0 + wave * 32 + 31;
  for (int kt = kt_lo; kt < kt_hi; kt++) {
    const int k0 = kt * 64;
    __syncthreads();  // previous tile fully consumed by all waves
    #pragma unroll
    for (int t = 0; t < 4; t++) { GLD16(kp[t], kl[t]); kp[t] += 64 * rs; }
    #pragma unroll
    for (int t = 0; t < 4; t++) { GLD16(vp[t], vl[t]); vp[t] += 64; }
    __syncthreads();  // compiler drains vmcnt before barrier -> tiles ready

    if (k0 > myrow_hi) continue;  // wave fully masked for this tile

    // S = Q K^T (log2 domain)
    f32x4 s[2][4] = {};
    #pragma unroll
    for (int ks = 0; ks < 4; ks++) {
      #pragma unroll
      for (int nt = 0; nt < 4; nt++) {
        bf16x8 kf = *(const bf16x8*)&Kl[(nt * 16 + l15) * 128 +
                                        (((ks * 4 + quad) ^ (l15 & 7)) * 8)];
        s[0][nt] = MFMA16(qf[0][ks], kf, s[0][nt]);
        s[1][nt] = MFMA16(qf[1][ks], kf, s[1][nt]);
      }
    }
    // causal mask: only the last two k-tiles can intersect the diagonal (uniform branch)
    if (kt >= nkt - 2) {
      #pragma unroll
      for (int mt = 0; mt < 2; mt++) {
        int rowb = q0 + wave * 32 + mt * 16 + quad * 4;
        #pragma unroll
        for (int nt = 0; nt < 4; nt++) {
          int col = k0 + nt * 16 + l15;
          #pragma unroll
          for (int r = 0; r < 4; r++)
            if (col > rowb + r) s[mt][nt][r] = MASKV;
        }
      }
    }
    // online softmax (log2 domain); l handled by ones-column MFMA in PV
    #pragma unroll
    for (int mt = 0; mt < 2; mt++) {
      f32x4 mx = s[mt][0];
      #pragma unroll
      for (int nt = 1; nt < 4; nt++)
        #pragma unroll
        for (int r = 0; r < 4; r++) mx[r] = fmaxf(mx[r], s[mt][nt][r]);
      #pragma unroll
      for (int d = 1; d < 16; d <<= 1) {
        f32x4 o = shfl_xor4(mx, d);
        #pragma unroll
        for (int r = 0; r < 4; r++) mx[r] = fmaxf(mx[r], o[r]);
      }
      // defer-max (T13): keep old running max while growth <= 8 (p bounded by 2^8)
      bool noresc = (mx[0] <= mrow[mt][0] + 8.f) && (mx[1] <= mrow[mt][1] + 8.f) &&
                    (mx[2] <= mrow[mt][2] + 8.f) && (mx[3] <= mrow[mt][3] + 8.f);
      if (!__all(noresc)) {
        f32x4 alpha;
        #pragma unroll
        for (int r = 0; r < 4; r++) {
          float mn = fmaxf(mrow[mt][r], mx[r]);
          alpha[r] = EXP2F(mrow[mt][r] - mn);
          mrow[mt][r] = mn;
        }
        #pragma unroll
        for (int no = 0; no < 8; no++)
          #pragma unroll
          for (int r = 0; r < 4; r++) oacc[mt][no][r] *= alpha[r];
        #pragma unroll
        for (int r = 0; r < 4; r++) lacc[mt][r] *= alpha[r];
      }
      // P = 2^(s - m): C-layout -> per-wave LDS (A-layout consumable); stride 68
      #pragma unroll
      for (int nt = 0; nt < 4; nt++)
        #pragma unroll
        for (int r = 0; r < 4; r++) {
          float p = EXP2F(s[mt][nt][r] - mrow[mt][r]);
          Pl[wave][(mt * 16 + quad * 4 + r) * 68 + nt * 16 + l15] = (bf16)p;
        }
    }
    // O += P V ; l += P 1 (ones-column row-sum, replaces shuffle-reduce)
    #pragma unroll
    for (int ks2 = 0; ks2 < 2; ks2++) {
      bf16x8 pf0 = *(const bf16x8*)&Pl[wave][l15 * 68 + ks2 * 32 + quad * 8];
      bf16x8 pf1 = *(const bf16x8*)&Pl[wave][(16 + l15) * 68 + ks2 * 32 + quad * 8];
      lacc[0] = MFMA16(pf0, ones8, lacc[0]);
      lacc[1] = MFMA16(pf1, ones8, lacc[1]);
      #pragma unroll
      for (int no = 0; no < 8; no++) {
        bf16x8 vf = *(const bf16x8*)&Vt[(no * 16 + l15) * 64 +
                                        (((ks2 * 4 + quad) ^ (l15 & 7)) * 8)];
        oacc[0][no] = MFMA16(pf0, vf, oacc[0][no]);
        oacc[1][no] = MFMA16(pf1, vf, oacc[1][no]);
      }
    }
  }

  if (!split) {
    // epilogue: normalize and write bf16
    #pragma unroll
    for (int mt = 0; mt < 2; mt++) {
      f32x4 linv;
      #pragma unroll
      for (int r = 0; r < 4; r++) linv[r] = 1.0f / lacc[mt][r];
      int row = q0 + wave * 32 + mt * 16 + quad * 4;
      #pragma unroll
      for (int no = 0; no < 8; no++) {
        int col = h * 128 + no * 16 + l15;
        #pragma unroll
        for (int r = 0; r < 4; r++)
          Obf[(size_t)(b * 2048 + row + r) * 2048 + col] = (bf16)(oacc[mt][no][r] * linv[r]);
      }
    }
  } else {
    // write f32 partial (unnormalized Oacc + m + l); merge kernel combines after this dispatch
    const int fidx = bh * 6 + (qt - 10);
    float* slot = Part + (size_t)(fidx * 2 + half) * SLOT_F32;
    #pragma unroll
    for (int mt = 0; mt < 2; mt++) {
      int row = wave * 32 + mt * 16 + quad * 4;  // local row 0..127
      #pragma unroll
      for (int no = 0; no < 8; no++) {
        int col = no * 16 + l15;
        #pragma unroll
        for (int r = 0; r < 4; r++)
          slot[(row + r) * 128 + col] = oacc[mt][no][r];
      }
    }
    if (l15 == 0) {
      #pragma unroll
      for (int mt = 0; mt < 2; mt++)
        #pragma unroll
        for (int r = 0; r < 4; r++) {
          int row = wave * 32 + mt * 16 + quad * 4 + r;
          slot[16384 + row] = mrow[mt][r];
          slot[16512 + row] = lacc[mt][r];
        }
    }
  }
}

// ---------------- deterministic split merge: Obf rows for qt>=10 ----------------
__global__ __launch_bounds__(256) void merge_split(const float* __restrict__ Part,
                                                   bf16* __restrict__ Obf) {
  const int fidx = blockIdx.x;        // 0..191
  const int bh = fidx / 6, qt = 10 + fidx % 6;
  const int b = bh >> 4, h = bh & 15;
  const int tid = threadIdx.x;
  const int cl = (tid & 31) * 4;      // column 0..124 step 4
  const int r0 = tid >> 5;            // row stream 0..7
  const float* s0 = Part + (size_t)(fidx * 2) * SLOT_F32;
  const float* s1 = s0 + SLOT_F32;
  #pragma unroll
  for (int i = 0; i < 16; i++) {
    int row = r0 + i * 8;
    float m0 = s0[16384 + row], l0 = s0[16512 + row];
    float m1 = s1[16384 + row], l1 = s1[16512 + row];
    float ms = fmaxf(m0, m1);
    float a0 = EXP2F(m0 - ms), a1 = EXP2F(m1 - ms);
    float linv = 1.0f / (l0 * a0 + l1 * a1);
    f32x4 v0 = *(const f32x4*)&s0[row * 128 + cl];
    f32x4 v1 = *(const f32x4*)&s1[row * 128 + cl];
    bf16x4v o;
    #pragma unroll
    for (int r = 0; r < 4; r++) o[r] = (bf16)((v0[r] * a0 + v1[r] * a1) * linv);
    *(bf16x4v*)&Obf[(size_t)(b * 2048 + qt * 128 + row) * 2048 + h * 128 + cl] = o;
  }
}

extern "C" void kernel_launch(void* const* d_in, const int* in_sizes, int n_in,
                              void* d_out, int out_size, void* d_ws, size_t ws_size,
                              hipStream_t stream) {
  const float* x  = (const float*)d_in[0];
  // d_in[1] = mask: always causal tril; handled analytically.
  const float* Wq = (const float*)d_in[2];
  const float* Wk = (const float*)d_in[3];
  const float* Wv = (const float*)d_in[4];
  const float* Wo = (const float*)d_in[5];
  float* out = (float*)d_out;

  // workspace layout (bf16 elements)
  bf16* Xb    = (bf16*)d_ws;           // 4096x2048
  bf16* Wqkvt = Xb + 8388608;          // 3072x2048 (transposed, fused Q|K|V)
  bf16* Wot   = Wqkvt + 6291456;       // 2048x2048 (transposed)
  bf16* QKV   = Wot + 4194304;         // 4096x3072 (V col-range unwritten/unused)
  bf16* Obf   = QKV + 12582912;        // 4096x2048
  bf16* Vg    = Obf + 8388608;         // 8 x 128 x 2048 (V^T per (b,kvh), written by gemm1)
  // total 83,886,080 bytes

  // split-K partials overlay Xb+Wqkvt (29.36 MB dead after gemm1):
  // 384 slots x 16640 f32 = 25.56 MB.
  float* Part = (float*)d_ws;

  const float qscale = (float)(0.08838834764831845 * 1.4426950408889634);

  prep<<<18432, 256, 0, stream>>>(x, Wq, Wk, Wv, Wo, Xb, Wqkvt, Wot, qscale);
  gemm_bt<<<dim3(24, 32), 256, 0, stream>>>(Xb, Wqkvt, QKV, Vg, 3072, 2048);
  gqa_attn<<<704, 256, 0, stream>>>(QKV, Vg, Obf, Part);
  merge_split<<<192, 256, 0, stream>>>(Part, Obf);
  gemm_bt64<<<dim3(16, 64), 128, 0, stream>>>(Obf, Wot, out, 2048, 2048);
}

// Round 12
// 303.701 us; speedup vs baseline: 1.0573x; 1.0573x over previous
//
#include <hip/hip_runtime.h>
#include <hip/hip_bf16.h>
#include <math.h>

typedef __bf16 bf16;
typedef bf16 bf16x8 __attribute__((ext_vector_type(8)));
typedef bf16 bf16x4v __attribute__((ext_vector_type(4)));
typedef float f32x4 __attribute__((ext_vector_type(4)));
typedef float f32x16 __attribute__((ext_vector_type(16)));
typedef unsigned int u32;
typedef u32 u32x4 __attribute__((ext_vector_type(4)));

#define GLD16(g, l) __builtin_amdgcn_global_load_lds(                          \
    (__attribute__((address_space(1))) void*)(g),                              \
    (__attribute__((address_space(3))) void*)(l), 16, 0, 0)

#define MFMA16(a, b, c) __builtin_amdgcn_mfma_f32_16x16x32_bf16((a), (b), (c), 0, 0, 0)
#define MFMA32(a, b, c) __builtin_amdgcn_mfma_f32_32x32x16_bf16((a), (b), (c), 0, 0, 0)

#if __has_builtin(__builtin_amdgcn_exp2f)
#define EXP2F(x) __builtin_amdgcn_exp2f(x)
#else
#define EXP2F(x) exp2f(x)
#endif

// pack 2 f32 -> 1 u32 of 2 bf16 (RNE; no builtin on gfx950 -> inline asm, per guide T12)
__device__ __forceinline__ u32 cvtpk_bf16(float lo, float hi_) {
  u32 r;
  asm("v_cvt_pk_bf16_f32 %0, %1, %2" : "=v"(r) : "v"(lo), "v"(hi_));
  return r;
}
// v_permlane32_swap_b32: a.hi32lanes <-> b.lo32lanes.
// after: a[l<32]=a, a[l>=32]=b[l-32]; b[l<32]=a[l+32], b[l>=32]=b.
__device__ __forceinline__ void pl32swap(u32& a, u32& b) {
  asm("v_permlane32_swap_b32 %0, %1" : "+v"(a), "+v"(b));
}

// ---------------- fused prep: cast x->bf16 + 4 weight transposes in ONE launch ----------------
// (verified R6/R8: absmax unchanged)
__global__ __launch_bounds__(256) void prep(const float* __restrict__ x,
                                            const float* __restrict__ Wq,
                                            const float* __restrict__ Wk,
                                            const float* __restrict__ Wv,
                                            const float* __restrict__ Wo,
                                            bf16* __restrict__ Xb,
                                            bf16* __restrict__ Wqkvt,
                                            bf16* __restrict__ Wot,
                                            float qscale) {
  const int id = blockIdx.x;
  const int tid = threadIdx.x;
  if (id >= 10240) {  // vector cast
    int i = (id - 10240) * 256 + tid;
    float4 v = ((const float4*)x)[i];
    bf16x4v o;
    o.x = (bf16)v.x; o.y = (bf16)v.y; o.z = (bf16)v.z; o.w = (bf16)v.w;
    ((bf16x4v*)Xb)[i] = o;
    return;
  }
  __shared__ float t[32][33];
  const float* in; bf16* out; int colsIn, outRowOff, bx, by; float scale;
  if (id < 4096)      { in = Wq; out = Wqkvt; colsIn = 2048; outRowOff = 0;    scale = qscale; bx = id & 63;          by = id >> 6; }
  else if (id < 5120) { in = Wk; out = Wqkvt; colsIn = 512;  outRowOff = 2048; scale = 1.0f;   bx = (id - 4096) & 15; by = (id - 4096) >> 4; }
  else if (id < 6144) { in = Wv; out = Wqkvt; colsIn = 512;  outRowOff = 2560; scale = 1.0f;   bx = (id - 5120) & 15; by = (id - 5120) >> 4; }
  else                { in = Wo; out = Wot;   colsIn = 2048; outRowOff = 0;    scale = 1.0f;   bx = (id - 6144) & 63; by = (id - 6144) >> 6; }
  const int c0 = bx * 32, r0 = by * 32;
  const int tx = tid & 31, ty = tid >> 5;
  #pragma unroll
  for (int i = 0; i < 32; i += 8)
    t[ty + i][tx] = in[(size_t)(r0 + ty + i) * colsIn + (c0 + tx)];
  __syncthreads();
  #pragma unroll
  for (int i = 0; i < 32; i += 8)
    out[(size_t)(outRowOff + c0 + ty + i) * 2048 + (r0 + tx)] = (bf16)(t[tx][ty + i] * scale);
}

// ---------------- m97-style GEMM (gemm1): A[M][K] bf16, Bt[N][K] bf16 -> C[M][N] ----------------
// One-tile-per-block, 768 blocks = 3 blocks/CU co-resident (verified R8).
// V col-tiles (colBase>=2560) write transposed bf16 directly to Vg[d][n] (verified R6/R8).
__global__ __launch_bounds__(256, 2) void gemm_bt(const bf16* __restrict__ A,
                                                  const bf16* __restrict__ Bt,
                                                  bf16* __restrict__ C,
                                                  bf16* __restrict__ Vg,
                                                  int N, int K) {
  __shared__ __attribute__((aligned(16))) bf16 As[128 * 32];
  __shared__ __attribute__((aligned(16))) bf16 Bs[128 * 32];
  const int tid = threadIdx.x;
  const int lane = tid & 63;
  const int wave = tid >> 6;
  const int wm = wave >> 1, wn = wave & 1;
  const int l15 = lane & 15, quad = lane >> 4;
  const int rowBase = blockIdx.y * 128;
  const int colBase = blockIdx.x * 128;

  f32x4 acc[4][4] = {};

  const int cb0 = wave * 64;
  const int c0 = cb0 + lane;
  const int c1 = c0 + 256;
  const bf16* a0 = A + (size_t)(rowBase + (c0 >> 2)) * K + (c0 & 3) * 8;
  const bf16* a1 = A + (size_t)(rowBase + (c1 >> 2)) * K + (c1 & 3) * 8;
  const bf16* b0 = Bt + (size_t)(colBase + (c0 >> 2)) * K + (c0 & 3) * 8;
  const bf16* b1 = Bt + (size_t)(colBase + (c1 >> 2)) * K + (c1 & 3) * 8;
  bf16* lA0 = &As[cb0 * 8];
  bf16* lA1 = &As[(cb0 + 256) * 8];
  bf16* lB0 = &Bs[cb0 * 8];
  bf16* lB1 = &Bs[(cb0 + 256) * 8];

  for (int k0 = 0; k0 < K; k0 += 32) {
    GLD16(a0 + k0, lA0);
    GLD16(a1 + k0, lA1);
    GLD16(b0 + k0, lB0);
    GLD16(b1 + k0, lB1);
    __syncthreads();
    bf16x8 af[4], bfr[4];
    #pragma unroll
    for (int i = 0; i < 4; i++)
      af[i] = *(const bf16x8*)&As[(wm * 64 + i * 16 + l15) * 32 + quad * 8];
    #pragma unroll
    for (int i = 0; i < 4; i++)
      bfr[i] = *(const bf16x8*)&Bs[(wn * 64 + i * 16 + l15) * 32 + quad * 8];
    #pragma unroll
    for (int i = 0; i < 4; i++)
      #pragma unroll
      for (int j = 0; j < 4; j++)
        acc[i][j] = MFMA16(af[i], bfr[j], acc[i][j]);
    __syncthreads();
  }

  if (colBase >= 2560) {
    const int kvh = (colBase - 2560) >> 7;
    #pragma unroll
    for (int i = 0; i < 4; i++) {
      int row = rowBase + wm * 64 + i * 16 + quad * 4;
      int bb = row >> 11;
      int n0 = row & 2047;
      #pragma unroll
      for (int j = 0; j < 4; j++) {
        int d = wn * 64 + j * 16 + l15;
        bf16x4v o;
        #pragma unroll
        for (int r = 0; r < 4; r++) o[r] = (bf16)acc[i][j][r];
        *(bf16x4v*)&Vg[((size_t)(bb * 4 + kvh) * 128 + d) * 2048 + n0] = o;
      }
    }
  } else {
    #pragma unroll
    for (int i = 0; i < 4; i++) {
      int row = rowBase + wm * 64 + i * 16 + quad * 4;
      #pragma unroll
      for (int j = 0; j < 4; j++) {
        int col = colBase + wn * 64 + j * 16 + l15;
        #pragma unroll
        for (int r = 0; r < 4; r++)
          C[(size_t)(row + r) * N + col] = (bf16)acc[i][j][r];
      }
    }
  }
}

// ---------------- gemm2: 64x128-tile, 128-thread (2-wave) variant -> f32 out ----------------
// (R11: measured null vs gemm_bt<float>; kept -- passed, bit-identical math.)
__global__ __launch_bounds__(128, 2) void gemm_bt64(const bf16* __restrict__ A,
                                                    const bf16* __restrict__ Bt,
                                                    float* __restrict__ C,
                                                    int N, int K) {
  __shared__ __attribute__((aligned(16))) bf16 As[64 * 32];
  __shared__ __attribute__((aligned(16))) bf16 Bs[128 * 32];
  const int tid = threadIdx.x;         // 0..127
  const int lane = tid & 63;
  const int wave = tid >> 6;           // 0..1
  const int l15 = lane & 15, quad = lane >> 4;
  const int rowBase = blockIdx.y * 64;
  const int colBase = blockIdx.x * 128;

  f32x4 acc[4][4] = {};

  const bf16* aP[2]; bf16* lAp[2];
  #pragma unroll
  for (int p = 0; p < 2; p++) {
    int s = p * 128 + tid;
    aP[p] = A + (size_t)(rowBase + (s >> 2)) * K + (s & 3) * 8;
    lAp[p] = &As[(p * 128 + wave * 64) * 8];
  }
  const bf16* bP[4]; bf16* lBp[4];
  #pragma unroll
  for (int p = 0; p < 4; p++) {
    int s = p * 128 + tid;
    bP[p] = Bt + (size_t)(colBase + (s >> 2)) * K + (s & 3) * 8;
    lBp[p] = &Bs[(p * 128 + wave * 64) * 8];
  }

  for (int k0 = 0; k0 < K; k0 += 32) {
    #pragma unroll
    for (int p = 0; p < 2; p++) GLD16(aP[p] + k0, lAp[p]);
    #pragma unroll
    for (int p = 0; p < 4; p++) GLD16(bP[p] + k0, lBp[p]);
    __syncthreads();
    bf16x8 af[4], bfr[4];
    #pragma unroll
    for (int i = 0; i < 4; i++)
      af[i] = *(const bf16x8*)&As[(i * 16 + l15) * 32 + quad * 8];
    #pragma unroll
    for (int i = 0; i < 4; i++)
      bfr[i] = *(const bf16x8*)&Bs[(wave * 64 + i * 16 + l15) * 32 + quad * 8];
    #pragma unroll
    for (int i = 0; i < 4; i++)
      #pragma unroll
      for (int j = 0; j < 4; j++)
        acc[i][j] = MFMA16(af[i], bfr[j], acc[i][j]);
    __syncthreads();
  }

  #pragma unroll
  for (int i = 0; i < 4; i++) {
    int row = rowBase + i * 16 + quad * 4;
    #pragma unroll
    for (int j = 0; j < 4; j++) {
      int col = colBase + wave * 64 + j * 16 + l15;
      #pragma unroll
      for (int r = 0; r < 4; r++)
        C[(size_t)(row + r) * N + col] = acc[i][j][r];
    }
  }
}

// ---------------- GQA attention v10: 32x32 swapped-operand core, in-register softmax ----------------
// Staging, barriers, BMAP split-K schedule: R8-EXACT (no new sync constructs).
// Core: S^T = mfma_32x32x16(K-frag, Q-frag) -> q-row is lane-local (col=lane&31).
//   row-max/row-sum: in-register over 32 regs + ONE shfl_xor(32) (was 32 bpermutes).
//   P^T -> PV B-frag via 16 cvt_pk + 8 permlane32_swap (T12; Pl LDS buffer DELETED).
//   O^T = mfma(V^T-frag, P^T-frag); Vg/Vt layouts unchanged.
// C/D map (m74/m101): col=lane&31, row=(r&3)+8*(r>>2)+4*(lane>>5).
#define MASKV (-1e30f)

// entry code = qt*4 + split*2 + half. CU c gets entries {c>>5, (c>>5)+8, (c>>5)+16}:
// every group of 3 sums to 34 tiles; longest block 20 tiles.
__device__ const unsigned char BMAP[22] = {
  28, 58, 24, 50, 20, 46, 36, 32,      // e0..e7:  qt7f qt14h0 qt6f qt12h0 qt5f qt11h0 qt9f qt8f
  62, 59, 54, 51, 47, 42, 55, 63,      // e8..e15: qt15h0 qt14h1 qt13h0 qt12h1 qt11h1 qt10h0 qt13h1 qt15h1
  0, 4, 8, 12, 16, 43                  // e16..e21: qt0f qt1f qt2f qt3f qt4f qt10h1
};

#define SLOT_F32 16640  // 128*128 Oacc + 128 m + 128 l

__global__ __launch_bounds__(256, 3) void gqa_attn(const bf16* __restrict__ QKV,
                                                   const bf16* __restrict__ Vg,
                                                   bf16* __restrict__ Obf,
                                                   float* __restrict__ Part) {
  __shared__ __attribute__((aligned(16))) bf16 Kl[64 * 128];   // [key][hd], chunk c' = c ^ (key&7)
  __shared__ __attribute__((aligned(16))) bf16 Vt[128 * 64];   // [hd][key], chunk c' = c ^ (d&7)

  const int tid = threadIdx.x;
  const int lane = tid & 63;
  const int wave = tid >> 6;
  const int l31 = lane & 31, hi = lane >> 5;

  const int e = BMAP[blockIdx.x >> 5];
  const int bh = blockIdx.x & 31;
  const int qt = e >> 2;
  const int split = (e >> 1) & 1;
  const int half = e & 1;
  const int b = bh >> 4, h = bh & 15, kvh = h >> 2;
  const int q0 = qt * 128;
  const int nkt = 2 * qt + 2;
  const int kt_lo = (split && half) ? (nkt >> 1) : 0;
  const int kt_hi = (split && !half) ? (nkt >> 1) : nkt;

  const size_t rs = 3072;
  const bf16* Qb  = QKV + (size_t)b * 2048 * rs + h * 128;
  const bf16* Kb  = QKV + (size_t)b * 2048 * rs + 2048 + kvh * 128;
  const bf16* Vgb = Vg + (size_t)(b * 4 + kvh) * 128 * 2048;

  const int qrow = q0 + wave * 32 + l31;  // this lane's q-row (col index of S^T)

  // Q as B-operand fragments: col=q (l31), k = hd slice hs*16 + hi*8 (pre-scaled by log2e*SCALE)
  bf16x8 qf[8];
  #pragma unroll
  for (int hs = 0; hs < 8; hs++)
    qf[hs] = *(const bf16x8*)&Qb[(size_t)qrow * rs + hs * 16 + hi * 8];

  // DMA staging pointers: R8-exact (swizzle folded into per-lane GLOBAL address).
  const bf16* kp[4]; const bf16* vp[4];
  bf16* kl[4]; bf16* vl[4];
  #pragma unroll
  for (int t = 0; t < 4; t++) {
    int keyl = wave * 16 + t * 4 + (lane >> 4);
    int ck = (lane & 15) ^ (4 * (t & 1) + (lane >> 4));  // (keyl&7) = 4*(t&1)+(lane>>4)
    kp[t] = Kb + (size_t)(kt_lo * 64 + keyl) * rs + ck * 8;
    kl[t] = &Kl[(wave * 16 + t * 4) * 128];
    int dl = wave * 32 + t * 8 + (lane >> 3);
    int cv = (lane & 7) ^ (lane >> 3);                   // (dl&7) = lane>>3
    vp[t] = Vgb + (size_t)dl * 2048 + kt_lo * 64 + cv * 8;
    vl[t] = &Vt[(wave * 32 + t * 8) * 64];
  }

  f32x16 oacc[4] = {};   // O^T: col=q (l31), row d = dg*32 + (r&3)+8*(r>>2)+4*hi
  float lacc = 0.f;
  float mrow = MASKV;

  const int myrow_hi = q0 + wave * 32 + 31;
  for (int kt = kt_lo; kt < kt_hi; kt++) {
    const int k0 = kt * 64;
    __syncthreads();  // previous tile fully consumed by all waves
    #pragma unroll
    for (int t = 0; t < 4; t++) { GLD16(kp[t], kl[t]); kp[t] += 64 * rs; }
    #pragma unroll
    for (int t = 0; t < 4; t++) { GLD16(vp[t], vl[t]); vp[t] += 64; }
    __syncthreads();  // compiler drains vmcnt before barrier -> tiles ready

    if (k0 > myrow_hi) continue;  // wave fully masked; barriers stay uniform

    // S^T = K * Q^T (log2 domain): D[key][q] per 32-key group kg
    f32x16 sacc[2] = {};
    #pragma unroll
    for (int hs = 0; hs < 8; hs++) {
      #pragma unroll
      for (int kg = 0; kg < 2; kg++) {
        bf16x8 kf = *(const bf16x8*)&Kl[(kg * 32 + l31) * 128 +
                                        (((hs * 2 + hi) ^ (l31 & 7)) * 8)];
        sacc[kg] = MFMA32(kf, qf[hs], sacc[kg]);
      }
    }
    // causal mask: key = k0 + kg*32 + (r&3)+8*(r>>2)+4*hi vs lane's qrow (uniform branch)
    if (kt >= nkt - 2) {
      #pragma unroll
      for (int kg = 0; kg < 2; kg++)
        #pragma unroll
        for (int r = 0; r < 16; r++) {
          int key = k0 + kg * 32 + (r & 3) + 8 * (r >> 2) + 4 * hi;
          if (key > qrow) sacc[kg][r] = MASKV;
        }
    }
    // row max: in-register over 32 + one cross-half shuffle
    float mx = sacc[0][0];
    #pragma unroll
    for (int kg = 0; kg < 2; kg++)
      #pragma unroll
      for (int r = 0; r < 16; r++) mx = fmaxf(mx, sacc[kg][r]);
    mx = fmaxf(mx, __shfl_xor(mx, 32));
    // defer-max (T13): keep old running max while growth <= 8 (p bounded by 2^8)
    bool noresc = (mx <= mrow + 8.f);
    if (!__all(noresc)) {
      float mn = fmaxf(mrow, mx);
      float alpha = EXP2F(mrow - mn);
      mrow = mn;
      #pragma unroll
      for (int dg = 0; dg < 4; dg++)
        #pragma unroll
        for (int r = 0; r < 16; r++) oacc[dg][r] *= alpha;
      lacc *= alpha;
    }
    // P = 2^(s-m), bf16-rounded (numerator and l from the SAME rounded values); row-sum in-register
    float ls = 0.f;
    #pragma unroll
    for (int kg = 0; kg < 2; kg++)
      #pragma unroll
      for (int r = 0; r < 16; r++) {
        float p = (float)(bf16)EXP2F(sacc[kg][r] - mrow);
        sacc[kg][r] = p;
        ls += p;
      }
    ls += __shfl_xor(ls, 32);
    lacc += ls;
    // pack P^T into PV B-fragments: cvt_pk pairs + permlane32_swap (one swap fills w0 and w2)
    u32 w[4][4];
    #pragma unroll
    for (int kg = 0; kg < 2; kg++) {
      u32 A0 = cvtpk_bf16(sacc[kg][0], sacc[kg][1]);
      u32 A1 = cvtpk_bf16(sacc[kg][2], sacc[kg][3]);
      u32 B0 = cvtpk_bf16(sacc[kg][4], sacc[kg][5]);
      u32 B1 = cvtpk_bf16(sacc[kg][6], sacc[kg][7]);
      pl32swap(A0, B0);
      pl32swap(A1, B1);
      w[kg * 2][0] = A0; w[kg * 2][1] = A1; w[kg * 2][2] = B0; w[kg * 2][3] = B1;
      u32 C0 = cvtpk_bf16(sacc[kg][8], sacc[kg][9]);
      u32 C1 = cvtpk_bf16(sacc[kg][10], sacc[kg][11]);
      u32 D0 = cvtpk_bf16(sacc[kg][12], sacc[kg][13]);
      u32 D1 = cvtpk_bf16(sacc[kg][14], sacc[kg][15]);
      pl32swap(C0, D0);
      pl32swap(C1, D1);
      w[kg * 2 + 1][0] = C0; w[kg * 2 + 1][1] = C1; w[kg * 2 + 1][2] = D0; w[kg * 2 + 1][3] = D1;
    }
    // O^T += V^T * P^T
    #pragma unroll
    for (int ks = 0; ks < 4; ks++) {
      u32x4 pw = {w[ks][0], w[ks][1], w[ks][2], w[ks][3]};
      bf16x8 pb = __builtin_bit_cast(bf16x8, pw);
      #pragma unroll
      for (int dg = 0; dg < 4; dg++) {
        bf16x8 va = *(const bf16x8*)&Vt[(dg * 32 + l31) * 64 +
                                        (((ks * 2 + hi) ^ (l31 & 7)) * 8)];
        oacc[dg] = MFMA32(va, pb, oacc[dg]);
      }
    }
  }

  if (!split) {
    // epilogue: normalize; lane holds q-row = qrow, d = dg*32 + rq*8 + hi*4 + j
    float linv = 1.0f / lacc;
    const size_t orow = (size_t)(b * 2048 + qrow) * 2048 + h * 128;
    #pragma unroll
    for (int dg = 0; dg < 4; dg++)
      #pragma unroll
      for (int rq = 0; rq < 4; rq++) {
        bf16x4v o;
        #pragma unroll
        for (int j = 0; j < 4; j++) o[j] = (bf16)(oacc[dg][rq * 4 + j] * linv);
        *(bf16x4v*)&Obf[orow + dg * 32 + rq * 8 + hi * 4] = o;
      }
  } else {
    // write f32 partial (unnormalized Oacc + m + l); merge kernel combines (format unchanged)
    const int fidx = bh * 6 + (qt - 10);
    float* slot = Part + (size_t)(fidx * 2 + half) * SLOT_F32;
    const int rl = wave * 32 + l31;
    #pragma unroll
    for (int dg = 0; dg < 4; dg++)
      #pragma unroll
      for (int rq = 0; rq < 4; rq++) {
        f32x4 o4;
        #pragma unroll
        for (int j = 0; j < 4; j++) o4[j] = oacc[dg][rq * 4 + j];
        *(f32x4*)&slot[rl * 128 + dg * 32 + rq * 8 + hi * 4] = o4;
      }
    if (hi == 0) {
      slot[16384 + rl] = mrow;
      slot[16512 + rl] = lacc;
    }
  }
}

// ---------------- deterministic split merge: Obf rows for qt>=10 ----------------
__global__ __launch_bounds__(256) void merge_split(const float* __restrict__ Part,
                                                   bf16* __restrict__ Obf) {
  const int fidx = blockIdx.x;        // 0..191
  const int bh = fidx / 6, qt = 10 + fidx % 6;
  const int b = bh >> 4, h = bh & 15;
  const int tid = threadIdx.x;
  const int cl = (tid & 31) * 4;      // column 0..124 step 4
  const int r0 = tid >> 5;            // row stream 0..7
  const float* s0 = Part + (size_t)(fidx * 2) * SLOT_F32;
  const float* s1 = s0 + SLOT_F32;
  #pragma unroll
  for (int i = 0; i < 16; i++) {
    int row = r0 + i * 8;
    float m0 = s0[16384 + row], l0 = s0[16512 + row];
    float m1 = s1[16384 + row], l1 = s1[16512 + row];
    float ms = fmaxf(m0, m1);
    float a0 = EXP2F(m0 - ms), a1 = EXP2F(m1 - ms);
    float linv = 1.0f / (l0 * a0 + l1 * a1);
    f32x4 v0 = *(const f32x4*)&s0[row * 128 + cl];
    f32x4 v1 = *(const f32x4*)&s1[row * 128 + cl];
    bf16x4v o;
    #pragma unroll
    for (int r = 0; r < 4; r++) o[r] = (bf16)((v0[r] * a0 + v1[r] * a1) * linv);
    *(bf16x4v*)&Obf[(size_t)(b * 2048 + qt * 128 + row) * 2048 + h * 128 + cl] = o;
  }
}

extern "C" void kernel_launch(void* const* d_in, const int* in_sizes, int n_in,
                              void* d_out, int out_size, void* d_ws, size_t ws_size,
                              hipStream_t stream) {
  const float* x  = (const float*)d_in[0];
  // d_in[1] = mask: always causal tril; handled analytically.
  const float* Wq = (const float*)d_in[2];
  const float* Wk = (const float*)d_in[3];
  const float* Wv = (const float*)d_in[4];
  const float* Wo = (const float*)d_in[5];
  float* out = (float*)d_out;

  // workspace layout (bf16 elements)
  bf16* Xb    = (bf16*)d_ws;           // 4096x2048
  bf16* Wqkvt = Xb + 8388608;          // 3072x2048 (transposed, fused Q|K|V)
  bf16* Wot   = Wqkvt + 6291456;       // 2048x2048 (transposed)
  bf16* QKV   = Wot + 4194304;         // 4096x3072 (V col-range unwritten/unused)
  bf16* Obf   = QKV + 12582912;        // 4096x2048
  bf16* Vg    = Obf + 8388608;         // 8 x 128 x 2048 (V^T per (b,kvh), written by gemm1)
  // total 83,886,080 bytes

  // split-K partials overlay Xb+Wqkvt (29.36 MB dead after gemm1):
  // 384 slots x 16640 f32 = 25.56 MB.
  float* Part = (float*)d_ws;

  const float qscale = (float)(0.08838834764831845 * 1.4426950408889634);

  prep<<<18432, 256, 0, stream>>>(x, Wq, Wk, Wv, Wo, Xb, Wqkvt, Wot, qscale);
  gemm_bt<<<dim3(24, 32), 256, 0, stream>>>(Xb, Wqkvt, QKV, Vg, 3072, 2048);
  gqa_attn<<<704, 256, 0, stream>>>(QKV, Vg, Obf, Part);
  merge_split<<<192, 256, 0, stream>>>(Part, Obf);
  gemm_bt64<<<dim3(16, 64), 128, 0, stream>>>(Obf, Wot, out, 2048, 2048);
}